// Round 2
// baseline (816.781 us; speedup 1.0000x reference)
//
#include <hip/hip_runtime.h>

typedef short short8 __attribute__((ext_vector_type(8)));
typedef float v4f   __attribute__((ext_vector_type(4)));

#define N_NODES 50000
#define N_EDGES 1600000
#define DIM     512

__device__ __forceinline__ float bf2f(unsigned short u) {
    unsigned int x = ((unsigned int)u) << 16;
    return __uint_as_float(x);
}
__device__ __forceinline__ unsigned short f2bf(float f) {
    unsigned int x = __float_as_uint(f);
    unsigned int r = x + 0x7fffu + ((x >> 16) & 1u);   // RTNE
    return (unsigned short)(r >> 16);
}

// ---------------- dtype detection --------------------------------------------
// flags[0] = 1 if float tensors are bf16 (else fp32)
// flags[1] = 1 if edge index tensors are int64 (else int32)
__global__ void detect_kernel(const unsigned int* __restrict__ xw,
                              const int* __restrict__ erow,
                              int* __restrict__ flags) {
    __shared__ int cbf, cz;
    if (threadIdx.x == 0) { cbf = 0; cz = 0; }
    __syncthreads();
    int lb = 0, lz = 0;
    for (int i = threadIdx.x; i < 1024; i += 256) {
        unsigned int w = xw[i];
        unsigned int e0 = (w >> 7) & 0xFFu;    // bf16 exponent of low half
        unsigned int e1 = (w >> 23) & 0xFFu;   // bf16 exponent of high half
        if (e0 >= 0x70u && e0 <= 0x8Fu && e1 >= 0x70u && e1 <= 0x8Fu) lb++;
        if (erow[2 * i + 1] == 0) lz++;
    }
    atomicAdd(&cbf, lb);
    atomicAdd(&cz, lz);
    __syncthreads();
    if (threadIdx.x == 0) {
        flags[0] = (cbf > 512) ? 1 : 0;
        flags[1] = (cz > 512) ? 1 : 0;
    }
}

// ---------------- W transpose -> canonical bf16 Wt[n][k] = W[k][n] ------------
__global__ void transpose_w(const void* __restrict__ Wv,
                            unsigned short* __restrict__ Wt,
                            const int* __restrict__ flags) {
    __shared__ unsigned short tile[32][33];
    const bool fb = flags[0] != 0;
    int bx = blockIdx.x * 32, by = blockIdx.y * 32;
    int tx = threadIdx.x, ty = threadIdx.y;           // block 32x8
    if (fb) {
        const unsigned short* W = (const unsigned short*)Wv;
        for (int r = ty; r < 32; r += 8)
            tile[r][tx] = W[(by + r) * DIM + bx + tx];
    } else {
        const float* W = (const float*)Wv;
        for (int r = ty; r < 32; r += 8)
            tile[r][tx] = f2bf(W[(by + r) * DIM + bx + tx]);
    }
    __syncthreads();
    for (int r = ty; r < 32; r += 8)
        Wt[(bx + r) * DIM + by + tx] = tile[tx][r];
}

// ---------------- GEMM: hidden = X @ W  (canonical bf16 out, fp32 acc) --------
#define TM 128
#define TN 128
#define BK 32
#define LP 40   // padded LDS row length (elements)

__global__ __launch_bounds__(256) void gemm_kernel(
        const void* __restrict__ Xv,
        const unsigned short* __restrict__ Wt,
        unsigned short* __restrict__ H,
        const int* __restrict__ flags) {
    __shared__ unsigned short lA[TM * LP];
    __shared__ unsigned short lB[TN * LP];

    const bool fb = flags[0] != 0;
    const unsigned short* Xb = (const unsigned short*)Xv;
    const float*          Xf = (const float*)Xv;

    const int t = threadIdx.x;
    const int mBase = blockIdx.y * TM;
    const int nBase = blockIdx.x * TN;
    const int w = t >> 6, lane = t & 63;
    const int lr = lane & 15, quad = lane >> 4;
    const int wr = w >> 1, wc = w & 1;

    v4f acc[4][4];
    #pragma unroll
    for (int i = 0; i < 4; ++i)
        #pragma unroll
        for (int j = 0; j < 4; ++j) acc[i][j] = (v4f)0.0f;

    for (int k0 = 0; k0 < DIM; k0 += BK) {
        #pragma unroll
        for (int rep = 0; rep < 2; ++rep) {
            int idx = rep * 256 + t;
            int r = idx >> 2;
            int cc = (idx & 3) * 8;
            int grow = mBase + r; if (grow >= N_NODES) grow = N_NODES - 1;
            size_t goff = (size_t)grow * DIM + k0 + cc;
            if (fb) {
                uint4 av = *(const uint4*)(Xb + goff);
                *(uint4*)(&lA[r * LP + cc]) = av;
            } else {
                float4 a0 = *(const float4*)(Xf + goff);
                float4 a1 = *(const float4*)(Xf + goff + 4);
                uint4 av;
                av.x = (unsigned int)f2bf(a0.x) | ((unsigned int)f2bf(a0.y) << 16);
                av.y = (unsigned int)f2bf(a0.z) | ((unsigned int)f2bf(a0.w) << 16);
                av.z = (unsigned int)f2bf(a1.x) | ((unsigned int)f2bf(a1.y) << 16);
                av.w = (unsigned int)f2bf(a1.z) | ((unsigned int)f2bf(a1.w) << 16);
                *(uint4*)(&lA[r * LP + cc]) = av;
            }
            uint4 bv = *(const uint4*)(Wt + (size_t)(nBase + r) * DIM + k0 + cc);
            *(uint4*)(&lB[r * LP + cc]) = bv;
        }
        __syncthreads();

        short8 bfr[4];
        #pragma unroll
        for (int j = 0; j < 4; ++j)
            bfr[j] = *(const short8*)(&lB[(wc * 64 + j * 16 + lr) * LP + quad * 8]);
        #pragma unroll
        for (int i = 0; i < 4; ++i) {
            short8 a = *(const short8*)(&lA[(wr * 64 + i * 16 + lr) * LP + quad * 8]);
            #pragma unroll
            for (int j = 0; j < 4; ++j)
                acc[i][j] = __builtin_amdgcn_mfma_f32_16x16x32_bf16(a, bfr[j], acc[i][j], 0, 0, 0);
        }
        __syncthreads();
    }

    // epilogue: D[m][n]: n = lane&15, m = quad*4 + reg
    #pragma unroll
    for (int i = 0; i < 4; ++i) {
        #pragma unroll
        for (int j = 0; j < 4; ++j) {
            #pragma unroll
            for (int r = 0; r < 4; ++r) {
                int gm = mBase + wr * 64 + i * 16 + quad * 4 + r;
                int gn = nBase + wc * 64 + j * 16 + lr;
                if (gm < N_NODES)
                    H[(size_t)gm * DIM + gn] = f2bf(acc[i][j][r]);
            }
        }
    }
}

// ---------------- counting sort: hist / scan / scatter ------------------------
__global__ void hist_kernel(const int* __restrict__ row, int* __restrict__ cnt,
                            const int* __restrict__ flags) {
    const bool f64 = flags[1] != 0;
    int i = blockIdx.x * 256 + threadIdx.x;
    if (i < N_EDGES) {
        int r = f64 ? row[2 * (size_t)i] : row[i];
        atomicAdd(&cnt[r], 1);
    }
}

__global__ __launch_bounds__(1024) void scan_kernel(
        const int* __restrict__ cnt, int* __restrict__ start, int* __restrict__ cursor) {
    __shared__ int part[1024];
    const int t = threadIdx.x;
    const int CH = 49;   // 1024*49 = 50176 >= 50000
    int lo = t * CH, hi = lo + CH;
    if (lo > N_NODES) lo = N_NODES;
    if (hi > N_NODES) hi = N_NODES;
    int s = 0;
    for (int i = lo; i < hi; ++i) s += cnt[i];
    part[t] = s;
    __syncthreads();
    for (int off = 1; off < 1024; off <<= 1) {
        int v = (t >= off) ? part[t - off] : 0;
        __syncthreads();
        part[t] += v;
        __syncthreads();
    }
    int run = (t > 0) ? part[t - 1] : 0;
    for (int i = lo; i < hi; ++i) {
        start[i] = run;
        cursor[i] = run;
        run += cnt[i];
    }
    if (t == 0) start[N_NODES] = N_EDGES;
}

__global__ void scatter_kernel(const int* __restrict__ row, const int* __restrict__ col,
                               const void* __restrict__ valv,
                               int* __restrict__ cursor,
                               int* __restrict__ sCol, float* __restrict__ sVal,
                               const int* __restrict__ flags) {
    const bool fb  = flags[0] != 0;
    const bool f64 = flags[1] != 0;
    int i = blockIdx.x * 256 + threadIdx.x;
    if (i < N_EDGES) {
        int r = f64 ? row[2 * (size_t)i] : row[i];
        int c = f64 ? col[2 * (size_t)i] : col[i];
        float v = fb ? bf2f(((const unsigned short*)valv)[i])
                     : ((const float*)valv)[i];
        int p = atomicAdd(&cursor[r], 1);
        sCol[p] = c;
        sVal[p] = v;
    }
}

// ---------------- gather: out[i] = sum_e val * hidden[col] + bias -------------
__global__ __launch_bounds__(256) void gather_kernel(
        const int* __restrict__ start, const int* __restrict__ sCol,
        const float* __restrict__ sVal, const unsigned short* __restrict__ H,
        const void* __restrict__ biasv, void* __restrict__ outv,
        const int* __restrict__ flags) {
    __shared__ int   lc[256];
    __shared__ float lv[256];
    const bool fb = flags[0] != 0;
    const int node = blockIdx.x;
    const int t = threadIdx.x;
    const int s = start[node], e = start[node + 1];
    float a0 = 0.f, a1 = 0.f;
    for (int base = s; base < e; base += 256) {
        int n = e - base; if (n > 256) n = 256;
        if (t < n) { lc[t] = sCol[base + t]; lv[t] = sVal[base + t]; }
        __syncthreads();
        for (int j = 0; j < n; ++j) {
            int c = lc[j];
            float v = lv[j];
            unsigned int h = *(const unsigned int*)(H + (size_t)c * DIM + t * 2);
            a0 += v * bf2f((unsigned short)(h & 0xffffu));
            a1 += v * bf2f((unsigned short)(h >> 16));
        }
        __syncthreads();
    }
    if (fb) {
        unsigned int bb = ((const unsigned int*)biasv)[t];
        a0 += bf2f((unsigned short)(bb & 0xffffu));
        a1 += bf2f((unsigned short)(bb >> 16));
        unsigned int o = (unsigned int)f2bf(a0) | ((unsigned int)f2bf(a1) << 16);
        ((unsigned int*)outv)[(size_t)node * (DIM / 2) + t] = o;
    } else {
        const float* bf = (const float*)biasv;
        a0 += bf[t * 2];
        a1 += bf[t * 2 + 1];
        float2 o; o.x = a0; o.y = a1;
        *(float2*)((float*)outv + (size_t)node * DIM + t * 2) = o;
    }
}

extern "C" void kernel_launch(void* const* d_in, const int* in_sizes, int n_in,
                              void* d_out, int out_size, void* d_ws, size_t ws_size,
                              hipStream_t stream) {
    const void* X    = d_in[0];
    const void* W    = d_in[1];
    const void* bias = d_in[2];
    const void* eval = d_in[3];
    const int*  erow = (const int*)d_in[4];
    const int*  ecol = (const int*)d_in[5];

    char* w = (char*)d_ws;
    size_t o = 0;
    int* flags = (int*)(w + o); o += 16;
    unsigned short* hidden = (unsigned short*)(w + o); o += (size_t)N_NODES * DIM * 2;  // 51.2 MB
    int*   sCol   = (int*)(w + o);   o += (size_t)N_EDGES * 4;                          // 6.4 MB
    float* sVal   = (float*)(w + o); o += (size_t)N_EDGES * 4;                          // 6.4 MB
    int*   cnt    = (int*)(w + o);   o += 200704;
    int*   start  = (int*)(w + o);   o += 200704;
    int*   cursor = (int*)(w + o);   o += 200704;
    unsigned short* Wt = (unsigned short*)(w + o); o += (size_t)DIM * DIM * 2;          // 0.5 MB

    hipMemsetAsync(cnt, 0, N_NODES * sizeof(int), stream);

    detect_kernel<<<1, 256, 0, stream>>>((const unsigned int*)X, erow, flags);
    transpose_w<<<dim3(16, 16), dim3(32, 8), 0, stream>>>(W, Wt, flags);
    gemm_kernel<<<dim3(DIM / TN, (N_NODES + TM - 1) / TM), 256, 0, stream>>>(X, Wt, hidden, flags);
    hist_kernel<<<(N_EDGES + 255) / 256, 256, 0, stream>>>(erow, cnt, flags);
    scan_kernel<<<1, 1024, 0, stream>>>(cnt, start, cursor);
    scatter_kernel<<<(N_EDGES + 255) / 256, 256, 0, stream>>>(erow, ecol, eval, cursor, sCol, sVal, flags);
    gather_kernel<<<N_NODES, 256, 0, stream>>>(start, sCol, sVal, hidden, bias, d_out, flags);
}

// Round 3
// 700.917 us; speedup vs baseline: 1.1653x; 1.1653x over previous
//
#include <hip/hip_runtime.h>

typedef short short8 __attribute__((ext_vector_type(8)));
typedef float v4f   __attribute__((ext_vector_type(4)));

#define N_NODES 50000
#define N_EDGES 1600000
#define DIM     512
#define SCAN_NB 49   // 49 blocks * 1024 elems = 50176 >= 50000

__device__ __forceinline__ float bf2f(unsigned short u) {
    unsigned int x = ((unsigned int)u) << 16;
    return __uint_as_float(x);
}
__device__ __forceinline__ unsigned short f2bf(float f) {
    unsigned int x = __float_as_uint(f);
    unsigned int r = x + 0x7fffu + ((x >> 16) & 1u);   // RTNE
    return (unsigned short)(r >> 16);
}

// ---------------- dtype detection --------------------------------------------
// flags[0] = 1 if float tensors are bf16 (else fp32)
// flags[1] = 1 if edge index tensors are int64 (else int32)
__global__ void detect_kernel(const unsigned int* __restrict__ xw,
                              const int* __restrict__ erow,
                              int* __restrict__ flags) {
    __shared__ int cbf, cz;
    if (threadIdx.x == 0) { cbf = 0; cz = 0; }
    __syncthreads();
    int lb = 0, lz = 0;
    for (int i = threadIdx.x; i < 1024; i += 256) {
        unsigned int w = xw[i];
        unsigned int e0 = (w >> 7) & 0xFFu;    // bf16 exponent of low half
        unsigned int e1 = (w >> 23) & 0xFFu;   // bf16 exponent of high half
        if (e0 >= 0x70u && e0 <= 0x8Fu && e1 >= 0x70u && e1 <= 0x8Fu) lb++;
        if (erow[2 * i + 1] == 0) lz++;
    }
    atomicAdd(&cbf, lb);
    atomicAdd(&cz, lz);
    __syncthreads();
    if (threadIdx.x == 0) {
        flags[0] = (cbf > 512) ? 1 : 0;
        flags[1] = (cz > 512) ? 1 : 0;
    }
}

// ---------------- W transpose -> canonical bf16 Wt[n][k] = W[k][n] ------------
__global__ void transpose_w(const void* __restrict__ Wv,
                            unsigned short* __restrict__ Wt,
                            const int* __restrict__ flags) {
    __shared__ unsigned short tile[32][33];
    const bool fb = flags[0] != 0;
    int bx = blockIdx.x * 32, by = blockIdx.y * 32;
    int tx = threadIdx.x, ty = threadIdx.y;           // block 32x8
    if (fb) {
        const unsigned short* W = (const unsigned short*)Wv;
        for (int r = ty; r < 32; r += 8)
            tile[r][tx] = W[(by + r) * DIM + bx + tx];
    } else {
        const float* W = (const float*)Wv;
        for (int r = ty; r < 32; r += 8)
            tile[r][tx] = f2bf(W[(by + r) * DIM + bx + tx]);
    }
    __syncthreads();
    for (int r = ty; r < 32; r += 8)
        Wt[(bx + r) * DIM + by + tx] = tile[tx][r];
}

// ---------------- GEMM: hidden = X @ W  (canonical bf16 out, fp32 acc) --------
#define TM 128
#define TN 128
#define BK 32
#define LP 40   // padded LDS row length (elements)

__global__ __launch_bounds__(256) void gemm_kernel(
        const void* __restrict__ Xv,
        const unsigned short* __restrict__ Wt,
        unsigned short* __restrict__ H,
        const int* __restrict__ flags) {
    __shared__ unsigned short lA[TM * LP];
    __shared__ unsigned short lB[TN * LP];

    const bool fb = flags[0] != 0;
    const unsigned short* Xb = (const unsigned short*)Xv;
    const float*          Xf = (const float*)Xv;

    const int t = threadIdx.x;
    const int mBase = blockIdx.y * TM;
    const int nBase = blockIdx.x * TN;
    const int w = t >> 6, lane = t & 63;
    const int lr = lane & 15, quad = lane >> 4;
    const int wr = w >> 1, wc = w & 1;

    v4f acc[4][4];
    #pragma unroll
    for (int i = 0; i < 4; ++i)
        #pragma unroll
        for (int j = 0; j < 4; ++j) acc[i][j] = (v4f)0.0f;

    for (int k0 = 0; k0 < DIM; k0 += BK) {
        #pragma unroll
        for (int rep = 0; rep < 2; ++rep) {
            int idx = rep * 256 + t;
            int r = idx >> 2;
            int cc = (idx & 3) * 8;
            int grow = mBase + r; if (grow >= N_NODES) grow = N_NODES - 1;
            size_t goff = (size_t)grow * DIM + k0 + cc;
            if (fb) {
                uint4 av = *(const uint4*)(Xb + goff);
                *(uint4*)(&lA[r * LP + cc]) = av;
            } else {
                float4 a0 = *(const float4*)(Xf + goff);
                float4 a1 = *(const float4*)(Xf + goff + 4);
                uint4 av;
                av.x = (unsigned int)f2bf(a0.x) | ((unsigned int)f2bf(a0.y) << 16);
                av.y = (unsigned int)f2bf(a0.z) | ((unsigned int)f2bf(a0.w) << 16);
                av.z = (unsigned int)f2bf(a1.x) | ((unsigned int)f2bf(a1.y) << 16);
                av.w = (unsigned int)f2bf(a1.z) | ((unsigned int)f2bf(a1.w) << 16);
                *(uint4*)(&lA[r * LP + cc]) = av;
            }
            uint4 bv = *(const uint4*)(Wt + (size_t)(nBase + r) * DIM + k0 + cc);
            *(uint4*)(&lB[r * LP + cc]) = bv;
        }
        __syncthreads();

        short8 bfr[4];
        #pragma unroll
        for (int j = 0; j < 4; ++j)
            bfr[j] = *(const short8*)(&lB[(wc * 64 + j * 16 + lr) * LP + quad * 8]);
        #pragma unroll
        for (int i = 0; i < 4; ++i) {
            short8 a = *(const short8*)(&lA[(wr * 64 + i * 16 + lr) * LP + quad * 8]);
            #pragma unroll
            for (int j = 0; j < 4; ++j)
                acc[i][j] = __builtin_amdgcn_mfma_f32_16x16x32_bf16(a, bfr[j], acc[i][j], 0, 0, 0);
        }
        __syncthreads();
    }

    // epilogue: D[m][n]: n = lane&15, m = quad*4 + reg
    #pragma unroll
    for (int i = 0; i < 4; ++i) {
        #pragma unroll
        for (int j = 0; j < 4; ++j) {
            #pragma unroll
            for (int r = 0; r < 4; ++r) {
                int gm = mBase + wr * 64 + i * 16 + quad * 4 + r;
                int gn = nBase + wc * 64 + j * 16 + lr;
                if (gm < N_NODES)
                    H[(size_t)gm * DIM + gn] = f2bf(acc[i][j][r]);
            }
        }
    }
}

// ---------------- counting sort: hist / 3-phase scan / scatter ----------------
__global__ void hist_kernel(const int* __restrict__ row, int* __restrict__ cnt,
                            const int* __restrict__ flags) {
    const bool f64 = flags[1] != 0;
    int i = blockIdx.x * 256 + threadIdx.x;
    if (i < N_EDGES) {
        int r = f64 ? row[2 * (size_t)i] : row[i];
        atomicAdd(&cnt[r], 1);
    }
}

__global__ __launch_bounds__(256) void scan1_kernel(const int* __restrict__ cnt,
                                                    int* __restrict__ bsum) {
    __shared__ int sh[256];
    const int b = blockIdx.x, t = threadIdx.x;
    int base = b * 1024 + t * 4;
    int s = 0;
    #pragma unroll
    for (int k = 0; k < 4; ++k) {
        int i = base + k;
        if (i < N_NODES) s += cnt[i];
    }
    sh[t] = s;
    __syncthreads();
    for (int off = 128; off > 0; off >>= 1) {
        if (t < off) sh[t] += sh[t + off];
        __syncthreads();
    }
    if (t == 0) bsum[b] = sh[0];
}

__global__ void scan2_kernel(const int* __restrict__ bsum, int* __restrict__ boff,
                             int* __restrict__ start) {
    if (threadIdx.x == 0) {
        int run = 0;
        for (int b = 0; b < SCAN_NB; ++b) { boff[b] = run; run += bsum[b]; }
        start[N_NODES] = N_EDGES;
    }
}

__global__ __launch_bounds__(256) void scan3_kernel(const int* __restrict__ cnt,
                                                    const int* __restrict__ boff,
                                                    int* __restrict__ start,
                                                    int* __restrict__ cursor) {
    __shared__ int sh[256];
    const int b = blockIdx.x, t = threadIdx.x;
    int base = b * 1024 + t * 4;
    int v[4];
    #pragma unroll
    for (int k = 0; k < 4; ++k) {
        int i = base + k;
        v[k] = (i < N_NODES) ? cnt[i] : 0;
    }
    int tsum = v[0] + v[1] + v[2] + v[3];
    sh[t] = tsum;
    __syncthreads();
    for (int off = 1; off < 256; off <<= 1) {
        int x = (t >= off) ? sh[t - off] : 0;
        __syncthreads();
        sh[t] += x;
        __syncthreads();
    }
    int excl = sh[t] - tsum + boff[b];
    #pragma unroll
    for (int k = 0; k < 4; ++k) {
        int i = base + k;
        if (i < N_NODES) { start[i] = excl; cursor[i] = excl; }
        excl += v[k];
    }
}

__global__ void scatter_kernel(const int* __restrict__ row, const int* __restrict__ col,
                               const void* __restrict__ valv,
                               int* __restrict__ cursor,
                               int2* __restrict__ sCV,
                               const int* __restrict__ flags) {
    const bool fb  = flags[0] != 0;
    const bool f64 = flags[1] != 0;
    int i = blockIdx.x * 256 + threadIdx.x;
    if (i < N_EDGES) {
        int r = f64 ? row[2 * (size_t)i] : row[i];
        int c = f64 ? col[2 * (size_t)i] : col[i];
        float v = fb ? bf2f(((const unsigned short*)valv)[i])
                     : ((const float*)valv)[i];
        int p = atomicAdd(&cursor[r], 1);
        int2 cv; cv.x = c; cv.y = __float_as_int(v);
        sCV[p] = cv;
    }
}

// ---------------- gather: out[i] = sum_e val * hidden[col] + bias -------------
// barrier-free: block-uniform edge stream, 4 waves each own 128 contiguous dims
__global__ __launch_bounds__(256) void gather_kernel(
        const int* __restrict__ start, const int2* __restrict__ sCV,
        const unsigned short* __restrict__ H,
        const void* __restrict__ biasv, void* __restrict__ outv,
        const int* __restrict__ flags) {
    const bool fb = flags[0] != 0;
    const int node = blockIdx.x;
    const int t = threadIdx.x;
    const int s = start[node], e = start[node + 1];
    float a0 = 0.f, a1 = 0.f;
    #pragma unroll 4
    for (int p = s; p < e; ++p) {
        int2 cv = sCV[p];                       // block-uniform -> broadcast
        float v = __int_as_float(cv.y);
        unsigned int h = *(const unsigned int*)(H + (size_t)cv.x * DIM + t * 2);
        a0 = fmaf(v, bf2f((unsigned short)(h & 0xffffu)), a0);
        a1 = fmaf(v, bf2f((unsigned short)(h >> 16)), a1);
    }
    if (fb) {
        unsigned int bb = ((const unsigned int*)biasv)[t];
        a0 += bf2f((unsigned short)(bb & 0xffffu));
        a1 += bf2f((unsigned short)(bb >> 16));
        unsigned int o = (unsigned int)f2bf(a0) | ((unsigned int)f2bf(a1) << 16);
        ((unsigned int*)outv)[(size_t)node * (DIM / 2) + t] = o;
    } else {
        const float* bf = (const float*)biasv;
        a0 += bf[t * 2];
        a1 += bf[t * 2 + 1];
        float2 o; o.x = a0; o.y = a1;
        *(float2*)((float*)outv + (size_t)node * DIM + t * 2) = o;
    }
}

extern "C" void kernel_launch(void* const* d_in, const int* in_sizes, int n_in,
                              void* d_out, int out_size, void* d_ws, size_t ws_size,
                              hipStream_t stream) {
    const void* X    = d_in[0];
    const void* W    = d_in[1];
    const void* bias = d_in[2];
    const void* eval = d_in[3];
    const int*  erow = (const int*)d_in[4];
    const int*  ecol = (const int*)d_in[5];

    char* w = (char*)d_ws;
    size_t o = 0;
    int* flags = (int*)(w + o); o += 256;
    unsigned short* hidden = (unsigned short*)(w + o); o += (size_t)N_NODES * DIM * 2;  // 51.2 MB
    int2*  sCV    = (int2*)(w + o);  o += (size_t)N_EDGES * 8;                          // 12.8 MB
    int*   cnt    = (int*)(w + o);   o += 200704;
    int*   start  = (int*)(w + o);   o += 200704;
    int*   cursor = (int*)(w + o);   o += 200704;
    unsigned short* Wt = (unsigned short*)(w + o); o += (size_t)DIM * DIM * 2;          // 0.5 MB
    int*   bsum   = (int*)(w + o);   o += 256;
    int*   boff   = (int*)(w + o);   o += 256;

    hipMemsetAsync(cnt, 0, N_NODES * sizeof(int), stream);

    detect_kernel<<<1, 256, 0, stream>>>((const unsigned int*)X, erow, flags);
    transpose_w<<<dim3(16, 16), dim3(32, 8), 0, stream>>>(W, Wt, flags);
    gemm_kernel<<<dim3(DIM / TN, (N_NODES + TM - 1) / TM), 256, 0, stream>>>(X, Wt, hidden, flags);
    hist_kernel<<<(N_EDGES + 255) / 256, 256, 0, stream>>>(erow, cnt, flags);
    scan1_kernel<<<SCAN_NB, 256, 0, stream>>>(cnt, bsum);
    scan2_kernel<<<1, 64, 0, stream>>>(bsum, boff, start);
    scan3_kernel<<<SCAN_NB, 256, 0, stream>>>(cnt, boff, start, cursor);
    scatter_kernel<<<(N_EDGES + 255) / 256, 256, 0, stream>>>(erow, ecol, eval, cursor, sCV, flags);
    gather_kernel<<<N_NODES, 256, 0, stream>>>(start, sCV, hidden, bias, d_out, flags);
}

// Round 4
// 690.721 us; speedup vs baseline: 1.1825x; 1.0148x over previous
//
#include <hip/hip_runtime.h>

typedef short short8 __attribute__((ext_vector_type(8)));
typedef float v4f   __attribute__((ext_vector_type(4)));

#define N_NODES 50000
#define N_EDGES 1600000
#define DIM     512
#define SCAN_NB 49   // 49 blocks * 1024 elems = 50176 >= 50000

__device__ __forceinline__ float bf2f(unsigned short u) {
    unsigned int x = ((unsigned int)u) << 16;
    return __uint_as_float(x);
}
__device__ __forceinline__ unsigned int f2bfu(float f) {
    unsigned int x = __float_as_uint(f);
    unsigned int r = x + 0x7fffu + ((x >> 16) & 1u);   // RTNE
    return r >> 16;
}

// ---------------- dtype detection --------------------------------------------
// flags[0] = 1 if float tensors are bf16 (else fp32)
// flags[1] = 1 if edge index tensors are int64 (else int32)
__global__ void detect_kernel(const unsigned int* __restrict__ xw,
                              const int* __restrict__ erow,
                              int* __restrict__ flags) {
    __shared__ int cbf, cz;
    if (threadIdx.x == 0) { cbf = 0; cz = 0; }
    __syncthreads();
    int lb = 0, lz = 0;
    for (int i = threadIdx.x; i < 1024; i += 256) {
        unsigned int w = xw[i];
        unsigned int e0 = (w >> 7) & 0xFFu;    // bf16 exponent of low half
        unsigned int e1 = (w >> 23) & 0xFFu;   // bf16 exponent of high half
        if (e0 >= 0x70u && e0 <= 0x8Fu && e1 >= 0x70u && e1 <= 0x8Fu) lb++;
        if (erow[2 * i + 1] == 0) lz++;
    }
    atomicAdd(&cbf, lb);
    atomicAdd(&cz, lz);
    __syncthreads();
    if (threadIdx.x == 0) {
        flags[0] = (cbf > 512) ? 1 : 0;
        flags[1] = (cz > 512) ? 1 : 0;
    }
}

// ---------------- X fp32 -> bf16 pre-convert (skipped if X already bf16) ------
__global__ __launch_bounds__(256) void convert_x(const void* __restrict__ Xv,
                                                 unsigned short* __restrict__ Xc,
                                                 const int* __restrict__ flags) {
    if (flags[0] != 0) return;   // data-dependent, stable across calls
    const float* Xf = (const float*)Xv;
    size_t i = ((size_t)blockIdx.x * 256 + threadIdx.x) * 8;
    float4 f0 = *(const float4*)(Xf + i);
    float4 f1 = *(const float4*)(Xf + i + 4);
    uint4 o;
    o.x = f2bfu(f0.x) | (f2bfu(f0.y) << 16);
    o.y = f2bfu(f0.z) | (f2bfu(f0.w) << 16);
    o.z = f2bfu(f1.x) | (f2bfu(f1.y) << 16);
    o.w = f2bfu(f1.z) | (f2bfu(f1.w) << 16);
    *(uint4*)(Xc + i) = o;
}

// ---------------- W transpose -> canonical bf16 Wt[n][k] = W[k][n] ------------
__global__ void transpose_w(const void* __restrict__ Wv,
                            unsigned short* __restrict__ Wt,
                            const int* __restrict__ flags) {
    __shared__ unsigned short tile[32][33];
    const bool fb = flags[0] != 0;
    int bx = blockIdx.x * 32, by = blockIdx.y * 32;
    int tx = threadIdx.x, ty = threadIdx.y;           // block 32x8
    if (fb) {
        const unsigned short* W = (const unsigned short*)Wv;
        for (int r = ty; r < 32; r += 8)
            tile[r][tx] = W[(by + r) * DIM + bx + tx];
    } else {
        const float* W = (const float*)Wv;
        for (int r = ty; r < 32; r += 8)
            tile[r][tx] = (unsigned short)f2bfu(W[(by + r) * DIM + bx + tx]);
    }
    __syncthreads();
    for (int r = ty; r < 32; r += 8)
        Wt[(bx + r) * DIM + by + tx] = tile[tx][r];
}

// ---------------- GEMM: hidden = X @ W  (canonical bf16 out, fp32 acc) --------
#define TM 128
#define TN 128
#define BK 32
#define LP 40   // padded LDS row length (elements) — conflict-free for b128 reads

__global__ __launch_bounds__(256) void gemm_kernel(
        const void* __restrict__ Xv,
        const unsigned short* __restrict__ Xc,
        const int have_xc,
        const unsigned short* __restrict__ Wt,
        unsigned short* __restrict__ H,
        const int* __restrict__ flags) {
    __shared__ unsigned short lA[TM * LP];
    __shared__ unsigned short lB[TN * LP];

    const bool fb = flags[0] != 0;
    const bool bfp = fb || (have_xc != 0);             // bf16 staging path?
    const unsigned short* Xb = fb ? (const unsigned short*)Xv : Xc;
    const float*          Xf = (const float*)Xv;

    const int t = threadIdx.x;
    const int mBase = blockIdx.y * TM;
    const int nBase = blockIdx.x * TN;
    const int w = t >> 6, lane = t & 63;
    const int lr = lane & 15, quad = lane >> 4;
    const int wr = w >> 1, wc = w & 1;

    v4f acc[4][4];
    #pragma unroll
    for (int i = 0; i < 4; ++i)
        #pragma unroll
        for (int j = 0; j < 4; ++j) acc[i][j] = (v4f)0.0f;

    for (int k0 = 0; k0 < DIM; k0 += BK) {
        #pragma unroll
        for (int rep = 0; rep < 2; ++rep) {
            int idx = rep * 256 + t;
            int r = idx >> 2;
            int cc = (idx & 3) * 8;
            int grow = mBase + r; if (grow >= N_NODES) grow = N_NODES - 1;
            size_t goff = (size_t)grow * DIM + k0 + cc;
            if (bfp) {
                uint4 av = *(const uint4*)(Xb + goff);
                *(uint4*)(&lA[r * LP + cc]) = av;
            } else {
                float4 a0 = *(const float4*)(Xf + goff);
                float4 a1 = *(const float4*)(Xf + goff + 4);
                uint4 av;
                av.x = f2bfu(a0.x) | (f2bfu(a0.y) << 16);
                av.y = f2bfu(a0.z) | (f2bfu(a0.w) << 16);
                av.z = f2bfu(a1.x) | (f2bfu(a1.y) << 16);
                av.w = f2bfu(a1.z) | (f2bfu(a1.w) << 16);
                *(uint4*)(&lA[r * LP + cc]) = av;
            }
            uint4 bv = *(const uint4*)(Wt + (size_t)(nBase + r) * DIM + k0 + cc);
            *(uint4*)(&lB[r * LP + cc]) = bv;
        }
        __syncthreads();

        short8 bfr[4];
        #pragma unroll
        for (int j = 0; j < 4; ++j)
            bfr[j] = *(const short8*)(&lB[(wc * 64 + j * 16 + lr) * LP + quad * 8]);
        #pragma unroll
        for (int i = 0; i < 4; ++i) {
            short8 a = *(const short8*)(&lA[(wr * 64 + i * 16 + lr) * LP + quad * 8]);
            #pragma unroll
            for (int j = 0; j < 4; ++j)
                acc[i][j] = __builtin_amdgcn_mfma_f32_16x16x32_bf16(a, bfr[j], acc[i][j], 0, 0, 0);
        }
        __syncthreads();
    }

    // epilogue: D[m][n]: n = lane&15, m = quad*4 + reg
    #pragma unroll
    for (int i = 0; i < 4; ++i) {
        #pragma unroll
        for (int j = 0; j < 4; ++j) {
            #pragma unroll
            for (int r = 0; r < 4; ++r) {
                int gm = mBase + wr * 64 + i * 16 + quad * 4 + r;
                int gn = nBase + wc * 64 + j * 16 + lr;
                if (gm < N_NODES)
                    H[(size_t)gm * DIM + gn] = (unsigned short)f2bfu(acc[i][j][r]);
            }
        }
    }
}

// ---------------- counting sort: hist / scan / scatter ------------------------
__global__ void hist_kernel(const int* __restrict__ row, int* __restrict__ cnt,
                            const int* __restrict__ flags) {
    const bool f64 = flags[1] != 0;
    int i = blockIdx.x * 256 + threadIdx.x;
    if (i < N_EDGES) {
        int r = f64 ? row[2 * (size_t)i] : row[i];
        atomicAdd(&cnt[r], 1);
    }
}

__global__ __launch_bounds__(256) void scan1_kernel(const int* __restrict__ cnt,
                                                    int* __restrict__ bsum) {
    __shared__ int sh[256];
    const int b = blockIdx.x, t = threadIdx.x;
    int base = b * 1024 + t * 4;
    int s = 0;
    #pragma unroll
    for (int k = 0; k < 4; ++k) {
        int i = base + k;
        if (i < N_NODES) s += cnt[i];
    }
    sh[t] = s;
    __syncthreads();
    for (int off = 128; off > 0; off >>= 1) {
        if (t < off) sh[t] += sh[t + off];
        __syncthreads();
    }
    if (t == 0) bsum[b] = sh[0];
}

// scan3 also folds in the cross-block offset (old scan2)
__global__ __launch_bounds__(256) void scan3_kernel(const int* __restrict__ cnt,
                                                    const int* __restrict__ bsum,
                                                    int* __restrict__ start,
                                                    int* __restrict__ cursor) {
    __shared__ int sh[256];
    __shared__ int boffs;
    const int b = blockIdx.x, t = threadIdx.x;
    if (t == 0) {
        int r = 0;
        #pragma unroll 8
        for (int i = 0; i < b; ++i) r += bsum[i];
        boffs = r;
        if (b == 0) start[N_NODES] = N_EDGES;
    }
    int base = b * 1024 + t * 4;
    int v[4];
    #pragma unroll
    for (int k = 0; k < 4; ++k) {
        int i = base + k;
        v[k] = (i < N_NODES) ? cnt[i] : 0;
    }
    int tsum = v[0] + v[1] + v[2] + v[3];
    sh[t] = tsum;
    __syncthreads();
    for (int off = 1; off < 256; off <<= 1) {
        int x = (t >= off) ? sh[t - off] : 0;
        __syncthreads();
        sh[t] += x;
        __syncthreads();
    }
    int excl = sh[t] - tsum + boffs;
    #pragma unroll
    for (int k = 0; k < 4; ++k) {
        int i = base + k;
        if (i < N_NODES) { start[i] = excl; cursor[i] = excl; }
        excl += v[k];
    }
}

__global__ void scatter_kernel(const int* __restrict__ row, const int* __restrict__ col,
                               const void* __restrict__ valv,
                               int* __restrict__ cursor,
                               int2* __restrict__ sCV,
                               const int* __restrict__ flags) {
    const bool fb  = flags[0] != 0;
    const bool f64 = flags[1] != 0;
    int i = blockIdx.x * 256 + threadIdx.x;
    if (i < N_EDGES) {
        int r = f64 ? row[2 * (size_t)i] : row[i];
        int c = f64 ? col[2 * (size_t)i] : col[i];
        float v = fb ? bf2f(((const unsigned short*)valv)[i])
                     : ((const float*)valv)[i];
        int p = atomicAdd(&cursor[r], 1);
        int2 cv; cv.x = c; cv.y = __float_as_int(v);
        sCV[p] = cv;
    }
}

// ---------------- gather: out[i] = sum_e val * hidden[col] + bias -------------
// 128 threads/block, each lane owns 4 dims via one uint2 (8B) load per edge
__global__ __launch_bounds__(128) void gather_kernel(
        const int* __restrict__ start, const int2* __restrict__ sCV,
        const unsigned short* __restrict__ H,
        const void* __restrict__ biasv, void* __restrict__ outv,
        const int* __restrict__ flags) {
    const bool fb = flags[0] != 0;
    const int node = blockIdx.x;
    const int t = threadIdx.x;              // dims 4t..4t+3
    const int s = start[node], e = start[node + 1];
    float a0 = 0.f, a1 = 0.f, a2 = 0.f, a3 = 0.f;
    #pragma unroll 4
    for (int p = s; p < e; ++p) {
        int2 cv = sCV[p];                   // block-uniform -> broadcast
        float v = __int_as_float(cv.y);
        uint2 h = *(const uint2*)(H + (size_t)cv.x * DIM + t * 4);
        a0 = fmaf(v, bf2f((unsigned short)(h.x & 0xffffu)), a0);
        a1 = fmaf(v, bf2f((unsigned short)(h.x >> 16)), a1);
        a2 = fmaf(v, bf2f((unsigned short)(h.y & 0xffffu)), a2);
        a3 = fmaf(v, bf2f((unsigned short)(h.y >> 16)), a3);
    }
    if (fb) {
        uint2 bb = ((const uint2*)biasv)[t];
        a0 += bf2f((unsigned short)(bb.x & 0xffffu));
        a1 += bf2f((unsigned short)(bb.x >> 16));
        a2 += bf2f((unsigned short)(bb.y & 0xffffu));
        a3 += bf2f((unsigned short)(bb.y >> 16));
        uint2 o;
        o.x = f2bfu(a0) | (f2bfu(a1) << 16);
        o.y = f2bfu(a2) | (f2bfu(a3) << 16);
        *(uint2*)((unsigned short*)outv + (size_t)node * DIM + t * 4) = o;
    } else {
        float4 bb = ((const float4*)biasv)[t];
        float4 o;
        o.x = a0 + bb.x; o.y = a1 + bb.y; o.z = a2 + bb.z; o.w = a3 + bb.w;
        *(float4*)((float*)outv + (size_t)node * DIM + t * 4) = o;
    }
}

extern "C" void kernel_launch(void* const* d_in, const int* in_sizes, int n_in,
                              void* d_out, int out_size, void* d_ws, size_t ws_size,
                              hipStream_t stream) {
    const void* X    = d_in[0];
    const void* W    = d_in[1];
    const void* bias = d_in[2];
    const void* eval = d_in[3];
    const int*  erow = (const int*)d_in[4];
    const int*  ecol = (const int*)d_in[5];

    char* w = (char*)d_ws;
    size_t o = 0;
    int* flags = (int*)(w + o); o += 256;
    unsigned short* hidden = (unsigned short*)(w + o); o += (size_t)N_NODES * DIM * 2;  // 51.2 MB
    int2*  sCV    = (int2*)(w + o);  o += (size_t)N_EDGES * 8;                          // 12.8 MB
    int*   cnt    = (int*)(w + o);   o += 200704;
    int*   start  = (int*)(w + o);   o += 200704;
    int*   cursor = (int*)(w + o);   o += 200704;
    unsigned short* Wt = (unsigned short*)(w + o); o += (size_t)DIM * DIM * 2;          // 0.5 MB
    int*   bsum   = (int*)(w + o);   o += 256;
    size_t base_end = o;
    unsigned short* Xc = (unsigned short*)(w + o);
    size_t need_xc = base_end + (size_t)N_NODES * DIM * 2;                              // +51.2 MB
    const int have_xc = (ws_size >= need_xc) ? 1 : 0;

    hipMemsetAsync(cnt, 0, N_NODES * sizeof(int), stream);

    detect_kernel<<<1, 256, 0, stream>>>((const unsigned int*)X, erow, flags);
    if (have_xc)
        convert_x<<<(N_NODES * DIM) / (256 * 8), 256, 0, stream>>>(X, Xc, flags);
    transpose_w<<<dim3(16, 16), dim3(32, 8), 0, stream>>>(W, Wt, flags);
    gemm_kernel<<<dim3(DIM / TN, (N_NODES + TM - 1) / TM), 256, 0, stream>>>(
        X, Xc, have_xc, Wt, hidden, flags);
    hist_kernel<<<(N_EDGES + 255) / 256, 256, 0, stream>>>(erow, cnt, flags);
    scan1_kernel<<<SCAN_NB, 256, 0, stream>>>(cnt, bsum);
    scan3_kernel<<<SCAN_NB, 256, 0, stream>>>(cnt, bsum, start, cursor);
    scatter_kernel<<<(N_EDGES + 255) / 256, 256, 0, stream>>>(erow, ecol, eval, cursor, sCV, flags);
    gather_kernel<<<N_NODES, 128, 0, stream>>>(start, sCV, hidden, bias, d_out, flags);
}